// Round 14
// baseline (396.855 us; speedup 1.0000x reference)
//
#include <hip/hip_runtime.h>
#include <hip/hip_bf16.h>
#include <math.h>

#define N_NODES 20000
#define F 128
#define NRBF 20
#define E_EDGES 320000
#define F3 (3 * F)   // 384
#define NCHUNK ((N_NODES + 255) / 256)   // 79

typedef __attribute__((ext_vector_type(8))) short bf16x8;
typedef __attribute__((ext_vector_type(4))) float f32x4;

__device__ __forceinline__ float silu_f(float x) {
    return x / (1.0f + __expf(-x));
}
__device__ __forceinline__ unsigned short bf_bits(float x) {
    __hip_bfloat16 b = __float2bfloat16(x);
    return *(unsigned short*)&b;
}
__device__ __forceinline__ float bfu2f(unsigned short u) {
    unsigned int x = ((unsigned int)u) << 16;
    return __uint_as_float(x);
}
// split x into bf16 hi + bf16 lo (x ~ hi + lo, ~15-bit effective mantissa)
__device__ __forceinline__ void bf_split(float x, unsigned short& hi, unsigned short& lo) {
    __hip_bfloat16 h = __float2bfloat16(x);
    float hf = __bfloat162float(h);
    __hip_bfloat16 l = __float2bfloat16(x - hf);
    hi = *(unsigned short*)&h;
    lo = *(unsigned short*)&l;
}

// ---------------------------------------------------------------------------
// Merged weight pre-swizzle (node MLP W1/W2 + update MLP WUV/M1/M2).
//   element(lane,j) = W[k = kc*32 + (lane>>4)*8 + j][n = ct*16 + (lane&15)]
// ---------------------------------------------------------------------------
__global__ __launch_bounds__(256) void w_swizzle_all(
    const float* __restrict__ W1, const float* __restrict__ W2,
    const float* __restrict__ WU, const float* __restrict__ WV,
    const float* __restrict__ M1, const float* __restrict__ M2,
    unsigned short* __restrict__ W1s, unsigned short* __restrict__ W2s,
    unsigned short* __restrict__ WUVs, unsigned short* __restrict__ M1s,
    unsigned short* __restrict__ M2s)
{
    int tid = blockIdx.x * 256 + threadIdx.x;
    if (tid < 8 * 4 * 64) {                                // W1
        int lane = tid & 63, kc = (tid >> 6) & 3, ct = tid >> 8;
        int n = ct * 16 + (lane & 15);
        int k0 = kc * 32 + (lane >> 4) * 8;
        #pragma unroll
        for (int j = 0; j < 8; ++j)
            W1s[tid * 8 + j] = bf_bits(W1[(k0 + j) * F + n]);
    } else if (tid < 8 * 4 * 64 + 24 * 4 * 64) {           // W2
        int t = tid - 8 * 4 * 64;
        int lane = t & 63, kc = (t >> 6) & 3, ct = t >> 8;
        int n = ct * 16 + (lane & 15);
        int k0 = kc * 32 + (lane >> 4) * 8;
        #pragma unroll
        for (int j = 0; j < 8; ++j)
            W2s[t * 8 + j] = bf_bits(W2[(k0 + j) * F3 + n]);
    } else if (tid < 8192 + 224 * 64) {                    // update-MLP weights
        int t2 = tid - 8192;
        int lane = t2 & 63;
        int set = t2 >> 6;
        if (set < 64) {                       // WUV: frag idx (ct*4+kc)
            int kc = set & 3, ct = set >> 2;
            int n = ct * 16 + (lane & 15);
            int k0 = kc * 32 + (lane >> 4) * 8;
            const float* W = (ct < 8) ? WU : WV;
            int nn = n & 127;
            #pragma unroll
            for (int j = 0; j < 8; ++j)
                WUVs[(size_t)(set * 64 + lane) * 8 + j] = bf_bits(W[(k0 + j) * F + nn]);
        } else if (set < 128) {               // M1: frag idx (ct*8+kc)
            int t = set - 64;
            int kc = t & 7, ct = t >> 3;
            int n = ct * 16 + (lane & 15);
            int k0 = kc * 32 + (lane >> 4) * 8;
            #pragma unroll
            for (int j = 0; j < 8; ++j)
                M1s[(size_t)(t * 64 + lane) * 8 + j] = bf_bits(M1[(k0 + j) * F + n]);
        } else {                              // M2: frag idx (ct*4+kc)
            int t = set - 128;
            int kc = t & 3, ct = t >> 2;
            int n = ct * 16 + (lane & 15);
            int k0 = kc * 32 + (lane >> 4) * 8;
            #pragma unroll
            for (int j = 0; j < 8; ++j)
                M2s[(size_t)(t * 64 + lane) * 8 + j] = bf_bits(M2[(k0 + j) * F3 + n]);
        }
    }
}

// ---------------------------------------------------------------------------
// Kernel A (MFMA): h = silu(s@W1+b1)@W2 + b2, bf16 inputs / fp32 accum.
// h stored as bf16 (R13). Grid = 2 blocks per 64-node tile.
// ---------------------------------------------------------------------------
#define SLD 136   // padded row stride (elements) for LDS tiles
__global__ __launch_bounds__(256) void node_mlp_mfma(
    const float* __restrict__ s, const float* __restrict__ b1,
    const float* __restrict__ b2,
    const unsigned short* __restrict__ W1s, const unsigned short* __restrict__ W2s,
    unsigned short* __restrict__ h)
{
    __shared__ unsigned short Sl[64][SLD];        // 17408 B
    __shared__ unsigned short Hid[4][16][SLD];    // 17408 B

    const int tid = threadIdx.x;
    const int lane = tid & 63, wave = tid >> 6;
    const int m = lane & 15, quad = lane >> 4;
    const int n0 = (blockIdx.x >> 1) * 64;
    const int ctbase = (blockIdx.x & 1) * 12;

    for (int i = tid; i < 64 * F; i += 256) {
        int r = i >> 7, c = i & 127;
        int nn = n0 + r;
        if (nn >= N_NODES) nn = N_NODES - 1;
        Sl[r][c] = bf_bits(s[(size_t)nn * F + c]);
    }
    __syncthreads();

    const int arow = wave * 16 + m;
    bf16x8 a1[4];
    #pragma unroll
    for (int kc = 0; kc < 4; ++kc)
        a1[kc] = *(const bf16x8*)&Sl[arow][kc * 32 + quad * 8];

    const bf16x8* W1f = (const bf16x8*)W1s;
    #pragma unroll
    for (int ct = 0; ct < 8; ++ct) {
        f32x4 acc = {0.f, 0.f, 0.f, 0.f};
        #pragma unroll
        for (int kc = 0; kc < 4; ++kc)
            acc = __builtin_amdgcn_mfma_f32_16x16x32_bf16(
                a1[kc], W1f[(ct * 4 + kc) * 64 + lane], acc, 0, 0, 0);
        float bias = b1[ct * 16 + m];
        #pragma unroll
        for (int r = 0; r < 4; ++r)
            Hid[wave][quad * 4 + r][ct * 16 + m] = bf_bits(silu_f(acc[r] + bias));
    }
    __syncthreads();

    bf16x8 a2[4];
    #pragma unroll
    for (int kc = 0; kc < 4; ++kc)
        a2[kc] = *(const bf16x8*)&Hid[wave][m][kc * 32 + quad * 8];

    const bf16x8* W2f = (const bf16x8*)W2s;
    #pragma unroll
    for (int ct2 = 0; ct2 < 12; ++ct2) {
        const int ct = ctbase + ct2;
        f32x4 acc = {0.f, 0.f, 0.f, 0.f};
        #pragma unroll
        for (int kc = 0; kc < 4; ++kc)
            acc = __builtin_amdgcn_mfma_f32_16x16x32_bf16(
                a2[kc], W2f[(ct * 4 + kc) * 64 + lane], acc, 0, 0, 0);
        float bias = b2[ct * 16 + m];
        #pragma unroll
        for (int r = 0; r < 4; ++r) {
            int node = n0 + wave * 16 + quad * 4 + r;
            if (node < N_NODES)
                h[(size_t)node * F3 + ct * 16 + m] = bf_bits(acc[r] + bias);
        }
    }
}

// ---------------------------------------------------------------------------
// CSR build: histogram -> 3-phase parallel scan -> scatter.
// R14: hist_kernel also produces the bf16 mirror of v (v16) via grid-stride
// float4->ushort4 (hist is atomic-latency-bound with idle BW; ~46 MB
// streaming rides along).
// ---------------------------------------------------------------------------
__global__ __launch_bounds__(256) void hist_kernel(const int* __restrict__ i_index,
                                                   int* __restrict__ counts,
                                                   const float* __restrict__ v,
                                                   unsigned short* __restrict__ v16)
{
    int e = blockIdx.x * 256 + threadIdx.x;
    if (e < E_EDGES) atomicAdd(&counts[i_index[e]], 1);

    const int total4 = N_NODES * F3 / 4;       // 1,920,000 float4 groups
    const int nthreads = gridDim.x * 256;
    for (int idx = e; idx < total4; idx += nthreads) {
        f32x4 x = *(const f32x4*)(v + (size_t)idx * 4);
        unsigned short y0 = bf_bits(x[0]);
        unsigned short y1 = bf_bits(x[1]);
        unsigned short y2 = bf_bits(x[2]);
        unsigned short y3 = bf_bits(x[3]);
        unsigned long long packed =
            (unsigned long long)y0 | ((unsigned long long)y1 << 16) |
            ((unsigned long long)y2 << 32) | ((unsigned long long)y3 << 48);
        *(unsigned long long*)(v16 + (size_t)idx * 4) = packed;
    }
}

__global__ __launch_bounds__(256) void scan_p1(const int* __restrict__ counts,
                                               int* __restrict__ row_start,
                                               int* __restrict__ chunk_sum)
{
    __shared__ int buf[256];
    const int tid = threadIdx.x;
    const int idx = blockIdx.x * 256 + tid;
    int val = (idx < N_NODES) ? counts[idx] : 0;
    buf[tid] = val;
    __syncthreads();
    for (int off = 1; off < 256; off <<= 1) {
        int t = (tid >= off) ? buf[tid - off] : 0;
        __syncthreads();
        buf[tid] += t;
        __syncthreads();
    }
    if (idx < N_NODES) row_start[idx] = buf[tid] - val;
    if (tid == 255) chunk_sum[blockIdx.x] = buf[255];
}

__global__ __launch_bounds__(128) void scan_p2(const int* __restrict__ chunk_sum,
                                               int* __restrict__ chunk_off)
{
    __shared__ int buf[128];
    const int tid = threadIdx.x;
    int val = (tid < NCHUNK) ? chunk_sum[tid] : 0;
    buf[tid] = val;
    __syncthreads();
    for (int off = 1; off < 128; off <<= 1) {
        int t = (tid >= off) ? buf[tid - off] : 0;
        __syncthreads();
        buf[tid] += t;
        __syncthreads();
    }
    if (tid < NCHUNK) chunk_off[tid] = buf[tid] - val;
}

__global__ __launch_bounds__(256) void scan_p3(int* __restrict__ row_start,
                                               const int* __restrict__ chunk_off,
                                               int* __restrict__ cursor)
{
    int idx = blockIdx.x * 256 + threadIdx.x;
    if (idx < N_NODES) {
        int vv = row_start[idx] + chunk_off[blockIdx.x];
        row_start[idx] = vv;
        cursor[idx] = vv;
    }
    if (idx == 0) row_start[N_NODES] = E_EDGES;
}

__global__ __launch_bounds__(256) void scatter_kernel(const int* __restrict__ i_index,
                                                      const int* __restrict__ j_index,
                                                      const float* __restrict__ dir,
                                                      int* __restrict__ cursor,
                                                      int* __restrict__ edge_ids,
                                                      int* __restrict__ edge_j,
                                                      float* __restrict__ edge_dir4)
{
    int e = blockIdx.x * 256 + threadIdx.x;
    if (e < E_EDGES) {
        int j = j_index[e];
        float dx = dir[(size_t)e * 3 + 0];
        float dy = dir[(size_t)e * 3 + 1];
        float dz = dir[(size_t)e * 3 + 2];
        int pos = atomicAdd(&cursor[i_index[e]], 1);
        edge_ids[pos] = e;
        edge_j[pos] = j;
        f32x4 d4 = {dx, dy, dz, 0.0f};
        *(f32x4*)(edge_dir4 + (size_t)pos * 4) = d4;
    }
}

// ---------------------------------------------------------------------------
// Kernel B: per-destination-node aggregation — R8 s/v split, FROZEN
// structure. R13: h gathered bf16. R14: v_j gathered bf16 (v16 mirror) —
// halves the last big random-gather stream. Base v[n] reads stay fp32.
// agg is latency/L2-fetch bound; structure changes all lose (R4/R7/R9/R10).
// ---------------------------------------------------------------------------
__global__ __launch_bounds__(256) void agg_kernel(
    const float* __restrict__ s, const float* __restrict__ v,
    const unsigned short* __restrict__ v16,
    const float* __restrict__ rbf,
    const float* __restrict__ Wr, const float* __restrict__ br,
    const unsigned short* __restrict__ h,
    const int* __restrict__ row_start, const int* __restrict__ edge_ids,
    const int* __restrict__ edge_j, const float* __restrict__ edge_dir4,
    float* __restrict__ s_agg, float* __restrict__ v_agg)
{
    const int tid = threadIdx.x;
    const int n = blockIdx.x;
    const int beg = row_start[n];
    const int end = row_start[n + 1];
    const float cc = 0.6283185307179586f;   // pi/5

    if (tid < 128) {
        // ---------------- s path (waves 0-1) ----------------
        const int f = tid;
        float wr0[NRBF];
        #pragma unroll
        for (int k = 0; k < NRBF; ++k)
            wr0[k] = Wr[k * F3 + f];
        const float br0 = br[f];

        float s_acc = s[n * F + f];

        for (int idx = beg; idx < end; ++idx) {
            const int e = edge_ids[idx];
            const int j = edge_j[idx];

            float x0 = br0;
            #pragma unroll
            for (int k = 0; k < NRBF; ++k)
                x0 += rbf[e * NRBF + k] * wr0[k];
            float w0 = (x0 < 5.0f) ? 0.5f * (__cosf(x0 * cc) + 1.0f) : 0.0f;

            s_acc += bfu2f(h[j * F3 + f]) * w0;
        }
        s_agg[n * F + f] = s_acc;
    } else {
        // ---------------- v path (waves 2-3) ----------------
        const int f = tid - 128;
        float wr1[NRBF], wr2[NRBF];
        #pragma unroll
        for (int k = 0; k < NRBF; ++k) {
            wr1[k] = Wr[k * F3 + F + f];
            wr2[k] = Wr[k * F3 + 2 * F + f];
        }
        const float br1 = br[F + f], br2 = br[2 * F + f];

        float v0 = v[n * F3 + f * 3 + 0];
        float v1 = v[n * F3 + f * 3 + 1];
        float v2 = v[n * F3 + f * 3 + 2];

        for (int idx = beg; idx < end; ++idx) {
            const int e = edge_ids[idx];
            const int j = edge_j[idx];

            float x1 = br1, x2 = br2;
            #pragma unroll
            for (int k = 0; k < NRBF; ++k) {
                float r = rbf[e * NRBF + k];
                x1 += r * wr1[k];
                x2 += r * wr2[k];
            }
            float w1 = (x1 < 5.0f) ? 0.5f * (__cosf(x1 * cc) + 1.0f) : 0.0f;
            float w2 = (x2 < 5.0f) ? 0.5f * (__cosf(x2 * cc) + 1.0f) : 0.0f;

            float hvs = bfu2f(h[j * F3 + F + f])     * w1;
            float hvv = bfu2f(h[j * F3 + 2 * F + f]) * w2;

            float dx = edge_dir4[idx * 4 + 0];
            float dy = edge_dir4[idx * 4 + 1];
            float dz = edge_dir4[idx * 4 + 2];

            float vj0 = bfu2f(v16[j * F3 + f * 3 + 0]);
            float vj1 = bfu2f(v16[j * F3 + f * 3 + 1]);
            float vj2 = bfu2f(v16[j * F3 + f * 3 + 2]);

            v0 += hvs * dx + hvv * vj0;
            v1 += hvs * dy + hvv * vj1;
            v2 += hvs * dz + hvv * vj2;
        }
        v_agg[n * F3 + f * 3 + 0] = v0;
        v_agg[n * F3 + f * 3 + 1] = v1;
        v_agg[n * F3 + f * 3 + 2] = v2;
    }
}

// ---------------------------------------------------------------------------
// Kernel C: per-node update via MFMA (R11 version, verbatim).
// ---------------------------------------------------------------------------
#define UB 16
__global__ __launch_bounds__(256) void update_mfma(
    const float* __restrict__ s_agg, const float* __restrict__ v_agg,
    const unsigned short* __restrict__ WUVs,
    const float* __restrict__ bU, const float* __restrict__ bV,
    const unsigned short* __restrict__ M1s, const float* __restrict__ bm1,
    const unsigned short* __restrict__ M2s, const float* __restrict__ bm2,
    float* __restrict__ s_out, float* __restrict__ v_out)
{
    __shared__ unsigned short VAh[48][SLD],  VAl[48][SLD];
    __shared__ unsigned short MIh[16][264],  MIl[16][264];
    __shared__ unsigned short HIh[16][SLD],  HIl[16][SLD];

    const int tid = threadIdx.x;
    const int lane = tid & 63, wave = tid >> 6;
    const int m = lane & 15, quad = lane >> 4;
    const int n0 = blockIdx.x * UB;

    for (int i = tid; i < UB * F3; i += 256) {
        int nl = i / F3, r = i - nl * F3;
        int f = r / 3, d = r - f * 3;
        unsigned short hi, lo;
        bf_split(v_agg[(size_t)n0 * F3 + i], hi, lo);
        VAh[d * 16 + nl][f] = hi;
        VAl[d * 16 + nl][f] = lo;
    }
    __syncthreads();

    f32x4 accU[3][2], accV[3][2];
    #pragma unroll
    for (int d = 0; d < 3; ++d)
        #pragma unroll
        for (int c = 0; c < 2; ++c) {
            accU[d][c] = (f32x4){0.f, 0.f, 0.f, 0.f};
            accV[d][c] = (f32x4){0.f, 0.f, 0.f, 0.f};
        }

    const bf16x8* Wf  = (const bf16x8*)WUVs;
    #pragma unroll
    for (int kc = 0; kc < 4; ++kc) {
        bf16x8 bu0 = Wf[((wave * 2 + 0) * 4 + kc) * 64 + lane];
        bf16x8 bu1 = Wf[((wave * 2 + 1) * 4 + kc) * 64 + lane];
        bf16x8 bv0 = Wf[((8 + wave * 2 + 0) * 4 + kc) * 64 + lane];
        bf16x8 bv1 = Wf[((8 + wave * 2 + 1) * 4 + kc) * 64 + lane];
        #pragma unroll
        for (int d = 0; d < 3; ++d) {
            bf16x8 ah = *(const bf16x8*)&VAh[d * 16 + m][kc * 32 + quad * 8];
            bf16x8 al = *(const bf16x8*)&VAl[d * 16 + m][kc * 32 + quad * 8];
            accU[d][0] = __builtin_amdgcn_mfma_f32_16x16x32_bf16(ah, bu0, accU[d][0], 0, 0, 0);
            accU[d][0] = __builtin_amdgcn_mfma_f32_16x16x32_bf16(al, bu0, accU[d][0], 0, 0, 0);
            accU[d][1] = __builtin_amdgcn_mfma_f32_16x16x32_bf16(ah, bu1, accU[d][1], 0, 0, 0);
            accU[d][1] = __builtin_amdgcn_mfma_f32_16x16x32_bf16(al, bu1, accU[d][1], 0, 0, 0);
            accV[d][0] = __builtin_amdgcn_mfma_f32_16x16x32_bf16(ah, bv0, accV[d][0], 0, 0, 0);
            accV[d][0] = __builtin_amdgcn_mfma_f32_16x16x32_bf16(al, bv0, accV[d][0], 0, 0, 0);
            accV[d][1] = __builtin_amdgcn_mfma_f32_16x16x32_bf16(ah, bv1, accV[d][1], 0, 0, 0);
            accV[d][1] = __builtin_amdgcn_mfma_f32_16x16x32_bf16(al, bv1, accV[d][1], 0, 0, 0);
        }
    }

    #pragma unroll
    for (int c = 0; c < 2; ++c) {
        int g = wave * 32 + c * 16 + m;
        float bu = bU[g], bv = bV[g];
        #pragma unroll
        for (int d = 0; d < 3; ++d)
            #pragma unroll
            for (int r = 0; r < 4; ++r) {
                accU[d][c][r] += bu;
                accV[d][c][r] += bv;
            }
        #pragma unroll
        for (int r = 0; r < 4; ++r) {
            int nl = quad * 4 + r;
            float nv = sqrtf(accV[0][c][r] * accV[0][c][r] +
                             accV[1][c][r] * accV[1][c][r] +
                             accV[2][c][r] * accV[2][c][r]);
            unsigned short hi, lo;
            bf_split(nv, hi, lo);
            MIh[nl][g] = hi; MIl[nl][g] = lo;
            bf_split(s_agg[(size_t)(n0 + nl) * F + g], hi, lo);
            MIh[nl][128 + g] = hi; MIl[nl][128 + g] = lo;
        }
    }
    __syncthreads();

    f32x4 acc2[2];
    acc2[0] = (f32x4){0.f, 0.f, 0.f, 0.f};
    acc2[1] = (f32x4){0.f, 0.f, 0.f, 0.f};
    const bf16x8* M1f = (const bf16x8*)M1s;
    #pragma unroll
    for (int kc = 0; kc < 8; ++kc) {
        bf16x8 ah = *(const bf16x8*)&MIh[m][kc * 32 + quad * 8];
        bf16x8 al = *(const bf16x8*)&MIl[m][kc * 32 + quad * 8];
        bf16x8 b0 = M1f[((wave * 2 + 0) * 8 + kc) * 64 + lane];
        bf16x8 b1 = M1f[((wave * 2 + 1) * 8 + kc) * 64 + lane];
        acc2[0] = __builtin_amdgcn_mfma_f32_16x16x32_bf16(ah, b0, acc2[0], 0, 0, 0);
        acc2[0] = __builtin_amdgcn_mfma_f32_16x16x32_bf16(al, b0, acc2[0], 0, 0, 0);
        acc2[1] = __builtin_amdgcn_mfma_f32_16x16x32_bf16(ah, b1, acc2[1], 0, 0, 0);
        acc2[1] = __builtin_amdgcn_mfma_f32_16x16x32_bf16(al, b1, acc2[1], 0, 0, 0);
    }
    #pragma unroll
    for (int c = 0; c < 2; ++c) {
        int g = wave * 32 + c * 16 + m;
        float bh = bm1[g];
        #pragma unroll
        for (int r = 0; r < 4; ++r) {
            unsigned short hi, lo;
            bf_split(silu_f(acc2[c][r] + bh), hi, lo);
            HIh[quad * 4 + r][g] = hi;
            HIl[quad * 4 + r][g] = lo;
        }
    }
    __syncthreads();

    f32x4 acc3[3][2];
    #pragma unroll
    for (int o = 0; o < 3; ++o)
        #pragma unroll
        for (int c = 0; c < 2; ++c)
            acc3[o][c] = (f32x4){0.f, 0.f, 0.f, 0.f};
    const bf16x8* M2f = (const bf16x8*)M2s;
    #pragma unroll
    for (int kc = 0; kc < 4; ++kc) {
        bf16x8 ah = *(const bf16x8*)&HIh[m][kc * 32 + quad * 8];
        bf16x8 al = *(const bf16x8*)&HIl[m][kc * 32 + quad * 8];
        #pragma unroll
        for (int o = 0; o < 3; ++o)
            #pragma unroll
            for (int c = 0; c < 2; ++c) {
                bf16x8 bb = M2f[(((o * 8) + wave * 2 + c) * 4 + kc) * 64 + lane];
                acc3[o][c] = __builtin_amdgcn_mfma_f32_16x16x32_bf16(ah, bb, acc3[o][c], 0, 0, 0);
                acc3[o][c] = __builtin_amdgcn_mfma_f32_16x16x32_bf16(al, bb, acc3[o][c], 0, 0, 0);
            }
    }

    #pragma unroll
    for (int c = 0; c < 2; ++c) {
        int g = wave * 32 + c * 16 + m;
        float bvv = bm2[g], bsv = bm2[128 + g], bss = bm2[256 + g];
        #pragma unroll
        for (int r = 0; r < 4; ++r) {
            int nl = quad * 4 + r;
            int n = n0 + nl;
            float a_vv = acc3[0][c][r] + bvv;
            float a_sv = acc3[1][c][r] + bsv;
            float a_ss = acc3[2][c][r] + bss;
            float dotuv = accU[0][c][r] * accV[0][c][r] +
                          accU[1][c][r] * accV[1][c][r] +
                          accU[2][c][r] * accV[2][c][r];
            s_out[(size_t)n * F + g] =
                s_agg[(size_t)n * F + g] + dotuv * a_sv + a_ss;
            #pragma unroll
            for (int d = 0; d < 3; ++d)
                v_out[(size_t)n * F3 + g * 3 + d] =
                    v_agg[(size_t)n * F3 + g * 3 + d] + a_vv * accU[d][c][r];
        }
    }
}

// ---------------------------------------------------------------------------
extern "C" void kernel_launch(void* const* d_in, const int* in_sizes, int n_in,
                              void* d_out, int out_size, void* d_ws, size_t ws_size,
                              hipStream_t stream) {
    const float* s    = (const float*)d_in[0];
    const float* v    = (const float*)d_in[1];
    const float* rbf  = (const float*)d_in[2];
    const float* dir  = (const float*)d_in[3];
    const float* W1   = (const float*)d_in[4];
    const float* b1   = (const float*)d_in[5];
    const float* W2   = (const float*)d_in[6];
    const float* b2   = (const float*)d_in[7];
    const float* Wr   = (const float*)d_in[8];
    const float* br   = (const float*)d_in[9];
    const float* WU   = (const float*)d_in[10];
    const float* bU   = (const float*)d_in[11];
    const float* WV   = (const float*)d_in[12];
    const float* bV   = (const float*)d_in[13];
    const float* M1   = (const float*)d_in[14];
    const float* bm1  = (const float*)d_in[15];
    const float* M2   = (const float*)d_in[16];
    const float* bm2  = (const float*)d_in[17];
    const int* i_index = (const int*)d_in[18];
    const int* j_index = (const int*)d_in[19];

    float* out_s = (float*)d_out;                     // N*F
    float* out_v = out_s + (size_t)N_NODES * F;       // N*F*3

    // workspace layout (h bf16: N*384 ushorts; v16 bf16 mirror of v)
    unsigned short* h  = (unsigned short*)d_ws;            // N*384 bf16
    unsigned short* v16 = h + (size_t)N_NODES * F3;        // N*384 bf16
    float* s_agg   = (float*)(v16 + (size_t)N_NODES * F3); // N*128
    float* v_agg   = s_agg + (size_t)N_NODES * F;          // N*384
    float* edge_dir4 = v_agg + (size_t)N_NODES * F3;       // E*4 (16B aligned)
    int*   counts  = (int*)(edge_dir4 + (size_t)E_EDGES * 4); // N
    int*   row_start = counts + N_NODES;                   // N+1
    int*   cursor  = row_start + N_NODES + 1;              // N
    int*   edge_ids = cursor + N_NODES;                    // E
    int*   edge_j  = edge_ids + E_EDGES;                   // E
    int*   chunk_sum = edge_j + E_EDGES;                   // 128
    int*   chunk_off = chunk_sum + 128;                    // 128
    unsigned short* W1s = (unsigned short*)(chunk_off + 128);  // 8*4*64*8
    unsigned short* W2s = W1s + 8 * 4 * 64 * 8;                // 24*4*64*8
    unsigned short* WUVs = W2s + 24 * 4 * 64 * 8;              // 16*4*64*8
    unsigned short* M1s  = WUVs + 16 * 4 * 64 * 8;             // 8*8*64*8
    unsigned short* M2s  = M1s + 8 * 8 * 64 * 8;               // 24*4*64*8

    hipMemsetAsync(counts, 0, sizeof(int) * N_NODES, stream);

    w_swizzle_all<<<88, 256, 0, stream>>>(W1, W2, WU, WV, M1, M2,
                                          W1s, W2s, WUVs, M1s, M2s);
    node_mlp_mfma<<<((N_NODES + 63) / 64) * 2, 256, 0, stream>>>(s, b1, b2, W1s, W2s, h);

    hist_kernel<<<(E_EDGES + 255) / 256, 256, 0, stream>>>(i_index, counts, v, v16);
    scan_p1<<<NCHUNK, 256, 0, stream>>>(counts, row_start, chunk_sum);
    scan_p2<<<1, 128, 0, stream>>>(chunk_sum, chunk_off);
    scan_p3<<<NCHUNK, 256, 0, stream>>>(row_start, chunk_off, cursor);
    scatter_kernel<<<(E_EDGES + 255) / 256, 256, 0, stream>>>(i_index, j_index, dir,
                                                              cursor, edge_ids, edge_j,
                                                              edge_dir4);

    agg_kernel<<<N_NODES, 256, 0, stream>>>(s, v, v16, rbf, Wr, br, h,
                                            row_start, edge_ids, edge_j, edge_dir4,
                                            s_agg, v_agg);

    update_mfma<<<N_NODES / UB, 256, 0, stream>>>(s_agg, v_agg, WUVs, bU, bV,
                                                  M1s, bm1, M2s, bm2, out_s, out_v);
}

// Round 15
// 382.511 us; speedup vs baseline: 1.0375x; 1.0375x over previous
//
#include <hip/hip_runtime.h>
#include <hip/hip_bf16.h>
#include <math.h>

#define N_NODES 20000
#define F 128
#define NRBF 20
#define E_EDGES 320000
#define F3 (3 * F)   // 384
#define NCHUNK ((N_NODES + 255) / 256)   // 79

typedef __attribute__((ext_vector_type(8))) short bf16x8;
typedef __attribute__((ext_vector_type(4))) float f32x4;

__device__ __forceinline__ float silu_f(float x) {
    return x / (1.0f + __expf(-x));
}
__device__ __forceinline__ unsigned short bf_bits(float x) {
    __hip_bfloat16 b = __float2bfloat16(x);
    return *(unsigned short*)&b;
}
__device__ __forceinline__ float bfu2f(unsigned short u) {
    unsigned int x = ((unsigned int)u) << 16;
    return __uint_as_float(x);
}
// split x into bf16 hi + bf16 lo (x ~ hi + lo, ~15-bit effective mantissa)
__device__ __forceinline__ void bf_split(float x, unsigned short& hi, unsigned short& lo) {
    __hip_bfloat16 h = __float2bfloat16(x);
    float hf = __bfloat162float(h);
    __hip_bfloat16 l = __float2bfloat16(x - hf);
    hi = *(unsigned short*)&h;
    lo = *(unsigned short*)&l;
}

// ---------------------------------------------------------------------------
// Merged weight pre-swizzle (node MLP W1/W2 + update MLP WUV/M1/M2).
//   element(lane,j) = W[k = kc*32 + (lane>>4)*8 + j][n = ct*16 + (lane&15)]
// ---------------------------------------------------------------------------
__global__ __launch_bounds__(256) void w_swizzle_all(
    const float* __restrict__ W1, const float* __restrict__ W2,
    const float* __restrict__ WU, const float* __restrict__ WV,
    const float* __restrict__ M1, const float* __restrict__ M2,
    unsigned short* __restrict__ W1s, unsigned short* __restrict__ W2s,
    unsigned short* __restrict__ WUVs, unsigned short* __restrict__ M1s,
    unsigned short* __restrict__ M2s)
{
    int tid = blockIdx.x * 256 + threadIdx.x;
    if (tid < 8 * 4 * 64) {                                // W1
        int lane = tid & 63, kc = (tid >> 6) & 3, ct = tid >> 8;
        int n = ct * 16 + (lane & 15);
        int k0 = kc * 32 + (lane >> 4) * 8;
        #pragma unroll
        for (int j = 0; j < 8; ++j)
            W1s[tid * 8 + j] = bf_bits(W1[(k0 + j) * F + n]);
    } else if (tid < 8 * 4 * 64 + 24 * 4 * 64) {           // W2
        int t = tid - 8 * 4 * 64;
        int lane = t & 63, kc = (t >> 6) & 3, ct = t >> 8;
        int n = ct * 16 + (lane & 15);
        int k0 = kc * 32 + (lane >> 4) * 8;
        #pragma unroll
        for (int j = 0; j < 8; ++j)
            W2s[t * 8 + j] = bf_bits(W2[(k0 + j) * F3 + n]);
    } else if (tid < 8192 + 224 * 64) {                    // update-MLP weights
        int t2 = tid - 8192;
        int lane = t2 & 63;
        int set = t2 >> 6;
        if (set < 64) {                       // WUV: frag idx (ct*4+kc)
            int kc = set & 3, ct = set >> 2;
            int n = ct * 16 + (lane & 15);
            int k0 = kc * 32 + (lane >> 4) * 8;
            const float* W = (ct < 8) ? WU : WV;
            int nn = n & 127;
            #pragma unroll
            for (int j = 0; j < 8; ++j)
                WUVs[(size_t)(set * 64 + lane) * 8 + j] = bf_bits(W[(k0 + j) * F + nn]);
        } else if (set < 128) {               // M1: frag idx (ct*8+kc)
            int t = set - 64;
            int kc = t & 7, ct = t >> 3;
            int n = ct * 16 + (lane & 15);
            int k0 = kc * 32 + (lane >> 4) * 8;
            #pragma unroll
            for (int j = 0; j < 8; ++j)
                M1s[(size_t)(t * 64 + lane) * 8 + j] = bf_bits(M1[(k0 + j) * F + n]);
        } else {                              // M2: frag idx (ct*4+kc)
            int t = set - 128;
            int kc = t & 3, ct = t >> 2;
            int n = ct * 16 + (lane & 15);
            int k0 = kc * 32 + (lane >> 4) * 8;
            #pragma unroll
            for (int j = 0; j < 8; ++j)
                M2s[(size_t)(t * 64 + lane) * 8 + j] = bf_bits(M2[(k0 + j) * F3 + n]);
        }
    }
}

// ---------------------------------------------------------------------------
// Kernel A (MFMA): h = silu(s@W1+b1)@W2 + b2, bf16 inputs / fp32 accum.
// h stored as bf16 (R13: halves agg's h-gather traffic; one extra rounding
// on an already-bf16-GEMM output). Grid = 2 blocks per 64-node tile.
// ---------------------------------------------------------------------------
#define SLD 136   // padded row stride (elements) for LDS tiles
__global__ __launch_bounds__(256) void node_mlp_mfma(
    const float* __restrict__ s, const float* __restrict__ b1,
    const float* __restrict__ b2,
    const unsigned short* __restrict__ W1s, const unsigned short* __restrict__ W2s,
    unsigned short* __restrict__ h)
{
    __shared__ unsigned short Sl[64][SLD];        // 17408 B
    __shared__ unsigned short Hid[4][16][SLD];    // 17408 B

    const int tid = threadIdx.x;
    const int lane = tid & 63, wave = tid >> 6;
    const int m = lane & 15, quad = lane >> 4;
    const int n0 = (blockIdx.x >> 1) * 64;
    const int ctbase = (blockIdx.x & 1) * 12;

    for (int i = tid; i < 64 * F; i += 256) {
        int r = i >> 7, c = i & 127;
        int nn = n0 + r;
        if (nn >= N_NODES) nn = N_NODES - 1;
        Sl[r][c] = bf_bits(s[(size_t)nn * F + c]);
    }
    __syncthreads();

    const int arow = wave * 16 + m;
    bf16x8 a1[4];
    #pragma unroll
    for (int kc = 0; kc < 4; ++kc)
        a1[kc] = *(const bf16x8*)&Sl[arow][kc * 32 + quad * 8];

    const bf16x8* W1f = (const bf16x8*)W1s;
    #pragma unroll
    for (int ct = 0; ct < 8; ++ct) {
        f32x4 acc = {0.f, 0.f, 0.f, 0.f};
        #pragma unroll
        for (int kc = 0; kc < 4; ++kc)
            acc = __builtin_amdgcn_mfma_f32_16x16x32_bf16(
                a1[kc], W1f[(ct * 4 + kc) * 64 + lane], acc, 0, 0, 0);
        float bias = b1[ct * 16 + m];
        #pragma unroll
        for (int r = 0; r < 4; ++r)
            Hid[wave][quad * 4 + r][ct * 16 + m] = bf_bits(silu_f(acc[r] + bias));
    }
    __syncthreads();

    bf16x8 a2[4];
    #pragma unroll
    for (int kc = 0; kc < 4; ++kc)
        a2[kc] = *(const bf16x8*)&Hid[wave][m][kc * 32 + quad * 8];

    const bf16x8* W2f = (const bf16x8*)W2s;
    #pragma unroll
    for (int ct2 = 0; ct2 < 12; ++ct2) {
        const int ct = ctbase + ct2;
        f32x4 acc = {0.f, 0.f, 0.f, 0.f};
        #pragma unroll
        for (int kc = 0; kc < 4; ++kc)
            acc = __builtin_amdgcn_mfma_f32_16x16x32_bf16(
                a2[kc], W2f[(ct * 4 + kc) * 64 + lane], acc, 0, 0, 0);
        float bias = b2[ct * 16 + m];
        #pragma unroll
        for (int r = 0; r < 4; ++r) {
            int node = n0 + wave * 16 + quad * 4 + r;
            if (node < N_NODES)
                h[(size_t)node * F3 + ct * 16 + m] = bf_bits(acc[r] + bias);
        }
    }
}

// ---------------------------------------------------------------------------
// CSR build: histogram -> 3-phase parallel scan -> scatter.
// (R14's v16 side-job removed: it cost ~12 us of streaming to save 3 us in
// the latency-bound agg — net negative.)
// ---------------------------------------------------------------------------
__global__ __launch_bounds__(256) void hist_kernel(const int* __restrict__ i_index,
                                                   int* __restrict__ counts)
{
    int e = blockIdx.x * 256 + threadIdx.x;
    if (e < E_EDGES) atomicAdd(&counts[i_index[e]], 1);
}

__global__ __launch_bounds__(256) void scan_p1(const int* __restrict__ counts,
                                               int* __restrict__ row_start,
                                               int* __restrict__ chunk_sum)
{
    __shared__ int buf[256];
    const int tid = threadIdx.x;
    const int idx = blockIdx.x * 256 + tid;
    int val = (idx < N_NODES) ? counts[idx] : 0;
    buf[tid] = val;
    __syncthreads();
    for (int off = 1; off < 256; off <<= 1) {
        int t = (tid >= off) ? buf[tid - off] : 0;
        __syncthreads();
        buf[tid] += t;
        __syncthreads();
    }
    if (idx < N_NODES) row_start[idx] = buf[tid] - val;
    if (tid == 255) chunk_sum[blockIdx.x] = buf[255];
}

__global__ __launch_bounds__(128) void scan_p2(const int* __restrict__ chunk_sum,
                                               int* __restrict__ chunk_off)
{
    __shared__ int buf[128];
    const int tid = threadIdx.x;
    int val = (tid < NCHUNK) ? chunk_sum[tid] : 0;
    buf[tid] = val;
    __syncthreads();
    for (int off = 1; off < 128; off <<= 1) {
        int t = (tid >= off) ? buf[tid - off] : 0;
        __syncthreads();
        buf[tid] += t;
        __syncthreads();
    }
    if (tid < NCHUNK) chunk_off[tid] = buf[tid] - val;
}

__global__ __launch_bounds__(256) void scan_p3(int* __restrict__ row_start,
                                               const int* __restrict__ chunk_off,
                                               int* __restrict__ cursor)
{
    int idx = blockIdx.x * 256 + threadIdx.x;
    if (idx < N_NODES) {
        int vv = row_start[idx] + chunk_off[blockIdx.x];
        row_start[idx] = vv;
        cursor[idx] = vv;
    }
    if (idx == 0) row_start[N_NODES] = E_EDGES;
}

__global__ __launch_bounds__(256) void scatter_kernel(const int* __restrict__ i_index,
                                                      const int* __restrict__ j_index,
                                                      const float* __restrict__ dir,
                                                      int* __restrict__ cursor,
                                                      int* __restrict__ edge_ids,
                                                      int* __restrict__ edge_j,
                                                      float* __restrict__ edge_dir4)
{
    int e = blockIdx.x * 256 + threadIdx.x;
    if (e < E_EDGES) {
        int j = j_index[e];
        float dx = dir[(size_t)e * 3 + 0];
        float dy = dir[(size_t)e * 3 + 1];
        float dz = dir[(size_t)e * 3 + 2];
        int pos = atomicAdd(&cursor[i_index[e]], 1);
        edge_ids[pos] = e;
        edge_j[pos] = j;
        f32x4 d4 = {dx, dy, dz, 0.0f};
        *(f32x4*)(edge_dir4 + (size_t)pos * 4) = d4;
    }
}

// ---------------------------------------------------------------------------
// Kernel B: per-destination-node aggregation — R8 s/v split, FROZEN
// structure; h gathered bf16 (R13). v gathers stay fp32 (R14 showed agg is
// latency-bound: halving v-bytes saved only 3 us while costing 12 in the
// producer — net negative). Structure changes all lose (R4/R7/R9/R10).
// ---------------------------------------------------------------------------
__global__ __launch_bounds__(256) void agg_kernel(
    const float* __restrict__ s, const float* __restrict__ v,
    const float* __restrict__ rbf,
    const float* __restrict__ Wr, const float* __restrict__ br,
    const unsigned short* __restrict__ h,
    const int* __restrict__ row_start, const int* __restrict__ edge_ids,
    const int* __restrict__ edge_j, const float* __restrict__ edge_dir4,
    float* __restrict__ s_agg, float* __restrict__ v_agg)
{
    const int tid = threadIdx.x;
    const int n = blockIdx.x;
    const int beg = row_start[n];
    const int end = row_start[n + 1];
    const float cc = 0.6283185307179586f;   // pi/5

    if (tid < 128) {
        // ---------------- s path (waves 0-1) ----------------
        const int f = tid;
        float wr0[NRBF];
        #pragma unroll
        for (int k = 0; k < NRBF; ++k)
            wr0[k] = Wr[k * F3 + f];
        const float br0 = br[f];

        float s_acc = s[n * F + f];

        for (int idx = beg; idx < end; ++idx) {
            const int e = edge_ids[idx];
            const int j = edge_j[idx];

            float x0 = br0;
            #pragma unroll
            for (int k = 0; k < NRBF; ++k)
                x0 += rbf[e * NRBF + k] * wr0[k];
            float w0 = (x0 < 5.0f) ? 0.5f * (__cosf(x0 * cc) + 1.0f) : 0.0f;

            s_acc += bfu2f(h[j * F3 + f]) * w0;
        }
        s_agg[n * F + f] = s_acc;
    } else {
        // ---------------- v path (waves 2-3) ----------------
        const int f = tid - 128;
        float wr1[NRBF], wr2[NRBF];
        #pragma unroll
        for (int k = 0; k < NRBF; ++k) {
            wr1[k] = Wr[k * F3 + F + f];
            wr2[k] = Wr[k * F3 + 2 * F + f];
        }
        const float br1 = br[F + f], br2 = br[2 * F + f];

        float v0 = v[n * F3 + f * 3 + 0];
        float v1 = v[n * F3 + f * 3 + 1];
        float v2 = v[n * F3 + f * 3 + 2];

        for (int idx = beg; idx < end; ++idx) {
            const int e = edge_ids[idx];
            const int j = edge_j[idx];

            float x1 = br1, x2 = br2;
            #pragma unroll
            for (int k = 0; k < NRBF; ++k) {
                float r = rbf[e * NRBF + k];
                x1 += r * wr1[k];
                x2 += r * wr2[k];
            }
            float w1 = (x1 < 5.0f) ? 0.5f * (__cosf(x1 * cc) + 1.0f) : 0.0f;
            float w2 = (x2 < 5.0f) ? 0.5f * (__cosf(x2 * cc) + 1.0f) : 0.0f;

            float hvs = bfu2f(h[j * F3 + F + f])     * w1;
            float hvv = bfu2f(h[j * F3 + 2 * F + f]) * w2;

            float dx = edge_dir4[idx * 4 + 0];
            float dy = edge_dir4[idx * 4 + 1];
            float dz = edge_dir4[idx * 4 + 2];

            float vj0 = v[j * F3 + f * 3 + 0];
            float vj1 = v[j * F3 + f * 3 + 1];
            float vj2 = v[j * F3 + f * 3 + 2];

            v0 += hvs * dx + hvv * vj0;
            v1 += hvs * dy + hvv * vj1;
            v2 += hvs * dz + hvv * vj2;
        }
        v_agg[n * F3 + f * 3 + 0] = v0;
        v_agg[n * F3 + f * 3 + 1] = v1;
        v_agg[n * F3 + f * 3 + 2] = v2;
    }
}

// ---------------------------------------------------------------------------
// Kernel C: per-node update via MFMA (R11 version, verbatim — the R12 LDS
// union + extra barriers regressed 66->90 us; separate buffers are faster).
// ---------------------------------------------------------------------------
#define UB 16
__global__ __launch_bounds__(256) void update_mfma(
    const float* __restrict__ s_agg, const float* __restrict__ v_agg,
    const unsigned short* __restrict__ WUVs,
    const float* __restrict__ bU, const float* __restrict__ bV,
    const unsigned short* __restrict__ M1s, const float* __restrict__ bm1,
    const unsigned short* __restrict__ M2s, const float* __restrict__ bm2,
    float* __restrict__ s_out, float* __restrict__ v_out)
{
    __shared__ unsigned short VAh[48][SLD],  VAl[48][SLD];
    __shared__ unsigned short MIh[16][264],  MIl[16][264];
    __shared__ unsigned short HIh[16][SLD],  HIl[16][SLD];

    const int tid = threadIdx.x;
    const int lane = tid & 63, wave = tid >> 6;
    const int m = lane & 15, quad = lane >> 4;
    const int n0 = blockIdx.x * UB;

    for (int i = tid; i < UB * F3; i += 256) {
        int nl = i / F3, r = i - nl * F3;
        int f = r / 3, d = r - f * 3;
        unsigned short hi, lo;
        bf_split(v_agg[(size_t)n0 * F3 + i], hi, lo);
        VAh[d * 16 + nl][f] = hi;
        VAl[d * 16 + nl][f] = lo;
    }
    __syncthreads();

    f32x4 accU[3][2], accV[3][2];
    #pragma unroll
    for (int d = 0; d < 3; ++d)
        #pragma unroll
        for (int c = 0; c < 2; ++c) {
            accU[d][c] = (f32x4){0.f, 0.f, 0.f, 0.f};
            accV[d][c] = (f32x4){0.f, 0.f, 0.f, 0.f};
        }

    const bf16x8* Wf  = (const bf16x8*)WUVs;
    #pragma unroll
    for (int kc = 0; kc < 4; ++kc) {
        bf16x8 bu0 = Wf[((wave * 2 + 0) * 4 + kc) * 64 + lane];
        bf16x8 bu1 = Wf[((wave * 2 + 1) * 4 + kc) * 64 + lane];
        bf16x8 bv0 = Wf[((8 + wave * 2 + 0) * 4 + kc) * 64 + lane];
        bf16x8 bv1 = Wf[((8 + wave * 2 + 1) * 4 + kc) * 64 + lane];
        #pragma unroll
        for (int d = 0; d < 3; ++d) {
            bf16x8 ah = *(const bf16x8*)&VAh[d * 16 + m][kc * 32 + quad * 8];
            bf16x8 al = *(const bf16x8*)&VAl[d * 16 + m][kc * 32 + quad * 8];
            accU[d][0] = __builtin_amdgcn_mfma_f32_16x16x32_bf16(ah, bu0, accU[d][0], 0, 0, 0);
            accU[d][0] = __builtin_amdgcn_mfma_f32_16x16x32_bf16(al, bu0, accU[d][0], 0, 0, 0);
            accU[d][1] = __builtin_amdgcn_mfma_f32_16x16x32_bf16(ah, bu1, accU[d][1], 0, 0, 0);
            accU[d][1] = __builtin_amdgcn_mfma_f32_16x16x32_bf16(al, bu1, accU[d][1], 0, 0, 0);
            accV[d][0] = __builtin_amdgcn_mfma_f32_16x16x32_bf16(ah, bv0, accV[d][0], 0, 0, 0);
            accV[d][0] = __builtin_amdgcn_mfma_f32_16x16x32_bf16(al, bv0, accV[d][0], 0, 0, 0);
            accV[d][1] = __builtin_amdgcn_mfma_f32_16x16x32_bf16(ah, bv1, accV[d][1], 0, 0, 0);
            accV[d][1] = __builtin_amdgcn_mfma_f32_16x16x32_bf16(al, bv1, accV[d][1], 0, 0, 0);
        }
    }

    #pragma unroll
    for (int c = 0; c < 2; ++c) {
        int g = wave * 32 + c * 16 + m;
        float bu = bU[g], bv = bV[g];
        #pragma unroll
        for (int d = 0; d < 3; ++d)
            #pragma unroll
            for (int r = 0; r < 4; ++r) {
                accU[d][c][r] += bu;
                accV[d][c][r] += bv;
            }
        #pragma unroll
        for (int r = 0; r < 4; ++r) {
            int nl = quad * 4 + r;
            float nv = sqrtf(accV[0][c][r] * accV[0][c][r] +
                             accV[1][c][r] * accV[1][c][r] +
                             accV[2][c][r] * accV[2][c][r]);
            unsigned short hi, lo;
            bf_split(nv, hi, lo);
            MIh[nl][g] = hi; MIl[nl][g] = lo;
            bf_split(s_agg[(size_t)(n0 + nl) * F + g], hi, lo);
            MIh[nl][128 + g] = hi; MIl[nl][128 + g] = lo;
        }
    }
    __syncthreads();

    f32x4 acc2[2];
    acc2[0] = (f32x4){0.f, 0.f, 0.f, 0.f};
    acc2[1] = (f32x4){0.f, 0.f, 0.f, 0.f};
    const bf16x8* M1f = (const bf16x8*)M1s;
    #pragma unroll
    for (int kc = 0; kc < 8; ++kc) {
        bf16x8 ah = *(const bf16x8*)&MIh[m][kc * 32 + quad * 8];
        bf16x8 al = *(const bf16x8*)&MIl[m][kc * 32 + quad * 8];
        bf16x8 b0 = M1f[((wave * 2 + 0) * 8 + kc) * 64 + lane];
        bf16x8 b1 = M1f[((wave * 2 + 1) * 8 + kc) * 64 + lane];
        acc2[0] = __builtin_amdgcn_mfma_f32_16x16x32_bf16(ah, b0, acc2[0], 0, 0, 0);
        acc2[0] = __builtin_amdgcn_mfma_f32_16x16x32_bf16(al, b0, acc2[0], 0, 0, 0);
        acc2[1] = __builtin_amdgcn_mfma_f32_16x16x32_bf16(ah, b1, acc2[1], 0, 0, 0);
        acc2[1] = __builtin_amdgcn_mfma_f32_16x16x32_bf16(al, b1, acc2[1], 0, 0, 0);
    }
    #pragma unroll
    for (int c = 0; c < 2; ++c) {
        int g = wave * 32 + c * 16 + m;
        float bh = bm1[g];
        #pragma unroll
        for (int r = 0; r < 4; ++r) {
            unsigned short hi, lo;
            bf_split(silu_f(acc2[c][r] + bh), hi, lo);
            HIh[quad * 4 + r][g] = hi;
            HIl[quad * 4 + r][g] = lo;
        }
    }
    __syncthreads();

    f32x4 acc3[3][2];
    #pragma unroll
    for (int o = 0; o < 3; ++o)
        #pragma unroll
        for (int c = 0; c < 2; ++c)
            acc3[o][c] = (f32x4){0.f, 0.f, 0.f, 0.f};
    const bf16x8* M2f = (const bf16x8*)M2s;
    #pragma unroll
    for (int kc = 0; kc < 4; ++kc) {
        bf16x8 ah = *(const bf16x8*)&HIh[m][kc * 32 + quad * 8];
        bf16x8 al = *(const bf16x8*)&HIl[m][kc * 32 + quad * 8];
        #pragma unroll
        for (int o = 0; o < 3; ++o)
            #pragma unroll
            for (int c = 0; c < 2; ++c) {
                bf16x8 bb = M2f[(((o * 8) + wave * 2 + c) * 4 + kc) * 64 + lane];
                acc3[o][c] = __builtin_amdgcn_mfma_f32_16x16x32_bf16(ah, bb, acc3[o][c], 0, 0, 0);
                acc3[o][c] = __builtin_amdgcn_mfma_f32_16x16x32_bf16(al, bb, acc3[o][c], 0, 0, 0);
            }
    }

    #pragma unroll
    for (int c = 0; c < 2; ++c) {
        int g = wave * 32 + c * 16 + m;
        float bvv = bm2[g], bsv = bm2[128 + g], bss = bm2[256 + g];
        #pragma unroll
        for (int r = 0; r < 4; ++r) {
            int nl = quad * 4 + r;
            int n = n0 + nl;
            float a_vv = acc3[0][c][r] + bvv;
            float a_sv = acc3[1][c][r] + bsv;
            float a_ss = acc3[2][c][r] + bss;
            float dotuv = accU[0][c][r] * accV[0][c][r] +
                          accU[1][c][r] * accV[1][c][r] +
                          accU[2][c][r] * accV[2][c][r];
            s_out[(size_t)n * F + g] =
                s_agg[(size_t)n * F + g] + dotuv * a_sv + a_ss;
            #pragma unroll
            for (int d = 0; d < 3; ++d)
                v_out[(size_t)n * F3 + g * 3 + d] =
                    v_agg[(size_t)n * F3 + g * 3 + d] + a_vv * accU[d][c][r];
        }
    }
}

// ---------------------------------------------------------------------------
extern "C" void kernel_launch(void* const* d_in, const int* in_sizes, int n_in,
                              void* d_out, int out_size, void* d_ws, size_t ws_size,
                              hipStream_t stream) {
    const float* s    = (const float*)d_in[0];
    const float* v    = (const float*)d_in[1];
    const float* rbf  = (const float*)d_in[2];
    const float* dir  = (const float*)d_in[3];
    const float* W1   = (const float*)d_in[4];
    const float* b1   = (const float*)d_in[5];
    const float* W2   = (const float*)d_in[6];
    const float* b2   = (const float*)d_in[7];
    const float* Wr   = (const float*)d_in[8];
    const float* br   = (const float*)d_in[9];
    const float* WU   = (const float*)d_in[10];
    const float* bU   = (const float*)d_in[11];
    const float* WV   = (const float*)d_in[12];
    const float* bV   = (const float*)d_in[13];
    const float* M1   = (const float*)d_in[14];
    const float* bm1  = (const float*)d_in[15];
    const float* M2   = (const float*)d_in[16];
    const float* bm2  = (const float*)d_in[17];
    const int* i_index = (const int*)d_in[18];
    const int* j_index = (const int*)d_in[19];

    float* out_s = (float*)d_out;                     // N*F
    float* out_v = out_s + (size_t)N_NODES * F;       // N*F*3

    // workspace layout (h is bf16: N*384 ushorts, 4B-aligned)
    unsigned short* h = (unsigned short*)d_ws;             // N*384 bf16
    float* s_agg   = (float*)(h + (size_t)N_NODES * F3);   // N*128
    float* v_agg   = s_agg + (size_t)N_NODES * F;          // N*384
    float* edge_dir4 = v_agg + (size_t)N_NODES * F3;       // E*4 (16B aligned)
    int*   counts  = (int*)(edge_dir4 + (size_t)E_EDGES * 4); // N
    int*   row_start = counts + N_NODES;                   // N+1
    int*   cursor  = row_start + N_NODES + 1;              // N
    int*   edge_ids = cursor + N_NODES;                    // E
    int*   edge_j  = edge_ids + E_EDGES;                   // E
    int*   chunk_sum = edge_j + E_EDGES;                   // 128
    int*   chunk_off = chunk_sum + 128;                    // 128
    unsigned short* W1s = (unsigned short*)(chunk_off + 128);  // 8*4*64*8
    unsigned short* W2s = W1s + 8 * 4 * 64 * 8;                // 24*4*64*8
    unsigned short* WUVs = W2s + 24 * 4 * 64 * 8;              // 16*4*64*8
    unsigned short* M1s  = WUVs + 16 * 4 * 64 * 8;             // 8*8*64*8
    unsigned short* M2s  = M1s + 8 * 8 * 64 * 8;               // 24*4*64*8

    hipMemsetAsync(counts, 0, sizeof(int) * N_NODES, stream);

    w_swizzle_all<<<88, 256, 0, stream>>>(W1, W2, WU, WV, M1, M2,
                                          W1s, W2s, WUVs, M1s, M2s);
    node_mlp_mfma<<<((N_NODES + 63) / 64) * 2, 256, 0, stream>>>(s, b1, b2, W1s, W2s, h);

    hist_kernel<<<(E_EDGES + 255) / 256, 256, 0, stream>>>(i_index, counts);
    scan_p1<<<NCHUNK, 256, 0, stream>>>(counts, row_start, chunk_sum);
    scan_p2<<<1, 128, 0, stream>>>(chunk_sum, chunk_off);
    scan_p3<<<NCHUNK, 256, 0, stream>>>(row_start, chunk_off, cursor);
    scatter_kernel<<<(E_EDGES + 255) / 256, 256, 0, stream>>>(i_index, j_index, dir,
                                                              cursor, edge_ids, edge_j,
                                                              edge_dir4);

    agg_kernel<<<N_NODES, 256, 0, stream>>>(s, v, rbf, Wr, br, h,
                                            row_start, edge_ids, edge_j, edge_dir4,
                                            s_agg, v_agg);

    update_mfma<<<N_NODES / UB, 256, 0, stream>>>(s_agg, v_agg, WUVs, bU, bV,
                                                  M1s, bm1, M2s, bm2, out_s, out_v);
}